// Round 1
// baseline (617.624 us; speedup 1.0000x reference)
//
#include <hip/hip_runtime.h>
#include <hip/hip_bf16.h>
#include <cstdint>
#include <cstddef>

typedef __attribute__((ext_vector_type(8))) short bf16x8;
typedef __attribute__((ext_vector_type(4))) float f32x4;

static constexpr int CB  = 2;
static constexpr int CS  = 2048;
static constexpr int CH  = 2048;
static constexpr int CNH = 32;
static constexpr int CNKV = 8;
static constexpr int CHD = 64;
static constexpr int CTHD = 3072; // (NH + 2*NKV)*HD

__device__ __forceinline__ void gload_lds16(const void* g, void* l) {
  __builtin_amdgcn_global_load_lds(
      (const __attribute__((address_space(1))) unsigned int*)g,
      (__attribute__((address_space(3))) unsigned int*)l, 16, 0, 0);
}

// ---------------- elementwise fp32 -> bf16 ----------------
__global__ void conv_bf16(const float* __restrict__ in, __hip_bfloat16* __restrict__ out, int n) {
  const int i = (blockIdx.x * 256 + threadIdx.x) * 4;
  if (i >= n) return;
  const float4 v = *(const float4*)(in + i);
  out[i]     = __float2bfloat16(v.x);
  out[i + 1] = __float2bfloat16(v.y);
  out[i + 2] = __float2bfloat16(v.z);
  out[i + 3] = __float2bfloat16(v.w);
}

// ---------------- tiled transpose + convert (fp32 RxC -> bf16 CxR) ----------------
__global__ __launch_bounds__(256) void transpose_conv(const float* __restrict__ in,
                                                      __hip_bfloat16* __restrict__ out,
                                                      int R, int Cc) {
  __shared__ float t[32][33];
  const int nbx = Cc >> 5;
  const int bx = blockIdx.x % nbx, by = blockIdx.x / nbx;
  const int c0 = bx << 5, r0 = by << 5;
  const int tx = threadIdx.x & 31, ty = threadIdx.x >> 5; // ty 0..7
#pragma unroll
  for (int j = 0; j < 32; j += 8)
    t[ty + j][tx] = in[(size_t)(r0 + ty + j) * Cc + c0 + tx];
  __syncthreads();
#pragma unroll
  for (int j = 0; j < 32; j += 8)
    out[(size_t)(c0 + ty + j) * R + r0 + tx] = __float2bfloat16(t[tx][ty + j]);
}

// ---------------- GEMM: C[MxN] = A[MxK] * Bt[NxK]^T  (m97-style 128x128 tile) ----------------
template <typename OutT>
__global__ __launch_bounds__(256) void gemm_bt(const __hip_bfloat16* __restrict__ A,
                                               const __hip_bfloat16* __restrict__ Bt,
                                               OutT* __restrict__ C, int M, int N, int K) {
  __shared__ __hip_bfloat16 As[128 * 32];
  __shared__ __hip_bfloat16 Bs[128 * 32];
  const int tid = threadIdx.x;
  const int lane = tid & 63;
  const int wave = tid >> 6;
  const int nTn = N >> 7;
  const int tm = blockIdx.x / nTn, tn = blockIdx.x % nTn;
  const size_t m0 = (size_t)tm * 128, n0 = (size_t)tn * 128;
  const __hip_bfloat16* Ag = A + m0 * K;
  const __hip_bfloat16* Bg = Bt + n0 * K;
  const int wr = wave >> 1, wc = wave & 1;
  const int rsel = lane & 15, k8 = (lane >> 4) << 3;

  f32x4 acc[4][4];
#pragma unroll
  for (int m = 0; m < 4; ++m)
#pragma unroll
    for (int n = 0; n < 4; ++n) acc[m][n] = (f32x4){0.f, 0.f, 0.f, 0.f};

  for (int k0 = 0; k0 < K; k0 += 32) {
    __syncthreads();
#pragma unroll
    for (int i = 0; i < 2; ++i) {
      const int c = i * 256 + tid;
      const int r = c >> 2, kq = (c & 3) << 3;
      gload_lds16(Ag + (size_t)r * K + k0 + kq, &As[(i * 256 + wave * 64) * 8]);
      gload_lds16(Bg + (size_t)r * K + k0 + kq, &Bs[(i * 256 + wave * 64) * 8]);
    }
    __syncthreads();
    bf16x8 af[4], bfr[4];
#pragma unroll
    for (int m = 0; m < 4; ++m)
      af[m] = *(const bf16x8*)&As[(wr * 64 + m * 16 + rsel) * 32 + k8];
#pragma unroll
    for (int n = 0; n < 4; ++n)
      bfr[n] = *(const bf16x8*)&Bs[(wc * 64 + n * 16 + rsel) * 32 + k8];
#pragma unroll
    for (int m = 0; m < 4; ++m)
#pragma unroll
      for (int n = 0; n < 4; ++n)
        acc[m][n] = __builtin_amdgcn_mfma_f32_16x16x32_bf16(af[m], bfr[n], acc[m][n], 0, 0, 0);
  }

  const int rowb = (lane >> 4) << 2;
#pragma unroll
  for (int m = 0; m < 4; ++m)
#pragma unroll
    for (int n = 0; n < 4; ++n) {
      const size_t r0 = m0 + wr * 64 + m * 16 + rowb;
      const size_t cc = n0 + wc * 64 + n * 16 + rsel;
#pragma unroll
      for (int j = 0; j < 4; ++j) {
        const float v = acc[m][n][j];
        if constexpr (sizeof(OutT) == 4)
          C[(r0 + j) * N + cc] = v;
        else
          C[(r0 + j) * N + cc] = __float2bfloat16(v);
      }
    }
}

// ---------------- RoPE + extract Q/K ----------------
__global__ void rope_extract(const __hip_bfloat16* __restrict__ qkv,
                             __hip_bfloat16* __restrict__ Q,
                             __hip_bfloat16* __restrict__ Kr) {
  const int idx = blockIdx.x * 256 + threadIdx.x;
  const int i = idx & 31;
  const int hs = (idx >> 5) % 40;     // 0..31 = Q heads, 32..39 = K heads
  const int r = idx / (40 * 32);      // b*S + s
  const int srow = r & (CS - 1);
  const int b = r >> 11;
  const float inv = exp2f(-(float)i * (13.287712379549449f / 32.0f)); // 10000^(-i/32)
  const float ang = (float)srow * inv;
  const float sn = sinf(ang), cs = cosf(ang);
  const int col = (hs < CNH) ? hs * CHD + 2 * i : CH + (hs - CNH) * CHD + 2 * i;
  const float t1 = __bfloat162float(qkv[(size_t)r * CTHD + col]);
  const float t2 = __bfloat162float(qkv[(size_t)r * CTHD + col + 1]);
  const float ev = t1 * cs - t2 * sn;
  const float ov = t1 * sn + t2 * cs;
  __hip_bfloat16* dst;
  if (hs < CNH)
    dst = Q + ((((size_t)b * CNH + hs) * CS + srow) * CHD + 2 * i);
  else
    dst = Kr + ((((size_t)b * CNKV + (hs - CNH)) * CS + srow) * CHD + 2 * i);
  dst[0] = __float2bfloat16(ev);
  dst[1] = __float2bfloat16(ov);
}

// ---------------- V extract + transpose: VT[b][kvh][d][s] ----------------
__global__ __launch_bounds__(256) void v_transpose(const __hip_bfloat16* __restrict__ qkv,
                                                   __hip_bfloat16* __restrict__ VT) {
  __shared__ __hip_bfloat16 t[64][72];
  const int bi = blockIdx.x;
  const int stile = bi & 31;
  const int kvh = (bi >> 5) & 7;
  const int b = bi >> 8;
  const int tx = threadIdx.x & 63;
  const int ty = threadIdx.x >> 6; // 0..3
  const int s0 = stile * 64;
#pragma unroll
  for (int j = 0; j < 16; ++j) {
    const int sl = ty * 16 + j;
    t[sl][tx] = qkv[(size_t)(b * CS + s0 + sl) * CTHD + (CH + CNKV * CHD) + kvh * CHD + tx];
  }
  __syncthreads();
#pragma unroll
  for (int j = 0; j < 16; ++j) {
    const int dl = ty * 16 + j;
    VT[(((size_t)b * CNKV + kvh) * CHD + dl) * CS + s0 + tx] = t[tx][dl];
  }
}

// ---------------- GQA causal flash attention ----------------
// grid: b(2) * h(32) * qtile(32); block 256 = 4 waves, each wave owns 16 q rows.
__global__ __launch_bounds__(256) void attn_fa(const __hip_bfloat16* __restrict__ Q,
                                               const __hip_bfloat16* __restrict__ Kr,
                                               const __hip_bfloat16* __restrict__ VT,
                                               const int* __restrict__ mask,
                                               __hip_bfloat16* __restrict__ O) {
  __shared__ __hip_bfloat16 Plds[4][16][72];
  const int bidx = blockIdx.x;
  const int qt = bidx & 31;
  const int h = (bidx >> 5) & 31;
  const int b = bidx >> 10;
  const int kvh = h >> 2; // groups = 4
  const int wave = threadIdx.x >> 6, lane = threadIdx.x & 63;
  const int q0 = qt * 64 + wave * 16;
  const int rsel = lane & 15, k8 = (lane >> 4) << 3;
  const int rowb = (lane >> 4) << 2;
  const __hip_bfloat16* Qp = Q + (((size_t)b * CNH + h) * CS + q0) * CHD;
  const __hip_bfloat16* Kp = Kr + ((size_t)b * CNKV + kvh) * CS * CHD;
  const __hip_bfloat16* Vp = VT + ((size_t)b * CNKV + kvh) * CHD * CS;
  const int* mp = mask + b * CS;
  __hip_bfloat16(*P)[72] = Plds[wave];

  bf16x8 qf[2];
  qf[0] = *(const bf16x8*)(Qp + rsel * CHD + k8);
  qf[1] = *(const bf16x8*)(Qp + rsel * CHD + 32 + k8);

  f32x4 o[4];
#pragma unroll
  for (int nt = 0; nt < 4; ++nt) o[nt] = (f32x4){0.f, 0.f, 0.f, 0.f};
  float mrun[4] = {-3e38f, -3e38f, -3e38f, -3e38f};
  float lrun[4] = {0.f, 0.f, 0.f, 0.f};

  const int nkb = qt + 1;
  for (int kb = 0; kb < nkb; ++kb) {
    const int key0 = kb * 64;
    f32x4 st[4];
#pragma unroll
    for (int kt = 0; kt < 4; ++kt) {
      const __hip_bfloat16* krow = Kp + (size_t)(key0 + kt * 16 + rsel) * CHD;
      const bf16x8 kf0 = *(const bf16x8*)(krow + k8);
      const bf16x8 kf1 = *(const bf16x8*)(krow + 32 + k8);
      f32x4 s = (f32x4){0.f, 0.f, 0.f, 0.f};
      s = __builtin_amdgcn_mfma_f32_16x16x32_bf16(qf[0], kf0, s, 0, 0, 0);
      s = __builtin_amdgcn_mfma_f32_16x16x32_bf16(qf[1], kf1, s, 0, 0, 0);
      st[kt] = s;
    }
    // scale + causal + key mask
#pragma unroll
    for (int kt = 0; kt < 4; ++kt) {
      const int key = key0 + kt * 16 + rsel;
      const bool kvalid = mp[key] > 0;
#pragma unroll
      for (int j = 0; j < 4; ++j) {
        float sv = st[kt][j] * 0.125f;
        const int qr = q0 + rowb + j;
        if (key > qr || !kvalid) sv = -1e9f;
        st[kt][j] = sv;
      }
    }
    // online softmax stats (reduce across the 16 key-lanes)
    float al[4];
#pragma unroll
    for (int j = 0; j < 4; ++j) {
      float v = fmaxf(fmaxf(st[0][j], st[1][j]), fmaxf(st[2][j], st[3][j]));
#pragma unroll
      for (int d = 1; d < 16; d <<= 1) v = fmaxf(v, __shfl_xor(v, d));
      const float mn = fmaxf(mrun[j], v);
      al[j] = exp2f((mrun[j] - mn) * 1.44269504f);
      mrun[j] = mn;
    }
    float ps[4] = {0.f, 0.f, 0.f, 0.f};
#pragma unroll
    for (int kt = 0; kt < 4; ++kt)
#pragma unroll
      for (int j = 0; j < 4; ++j) {
        const float p = exp2f((st[kt][j] - mrun[j]) * 1.44269504f);
        st[kt][j] = p;
        ps[j] += p;
      }
#pragma unroll
    for (int j = 0; j < 4; ++j) {
      float v = ps[j];
#pragma unroll
      for (int d = 1; d < 16; d <<= 1) v += __shfl_xor(v, d);
      lrun[j] = lrun[j] * al[j] + v;
#pragma unroll
      for (int nt = 0; nt < 4; ++nt) o[nt][j] *= al[j];
    }
    // P (C/D layout) -> LDS -> A-fragment layout (wave-private buffer, in-order DS ops)
#pragma unroll
    for (int kt = 0; kt < 4; ++kt)
#pragma unroll
      for (int j = 0; j < 4; ++j)
        P[rowb + j][kt * 16 + rsel] = __float2bfloat16(st[kt][j]);
    const bf16x8 pa0 = *(const bf16x8*)&P[rsel][k8];
    const bf16x8 pa1 = *(const bf16x8*)&P[rsel][32 + k8];
#pragma unroll
    for (int nt = 0; nt < 4; ++nt) {
      const __hip_bfloat16* vrow = Vp + (size_t)(nt * 16 + rsel) * CS + key0;
      const bf16x8 vf0 = *(const bf16x8*)(vrow + k8);
      const bf16x8 vf1 = *(const bf16x8*)(vrow + 32 + k8);
      o[nt] = __builtin_amdgcn_mfma_f32_16x16x32_bf16(pa0, vf0, o[nt], 0, 0, 0);
      o[nt] = __builtin_amdgcn_mfma_f32_16x16x32_bf16(pa1, vf1, o[nt], 0, 0, 0);
    }
  }

#pragma unroll
  for (int j = 0; j < 4; ++j) {
    const int qr = q0 + rowb + j;
    const float qm = (mp[qr] > 0) ? 1.0f : 0.0f;
    const float inv = qm / fmaxf(lrun[j], 1e-20f);
#pragma unroll
    for (int nt = 0; nt < 4; ++nt)
      O[(((size_t)b * CS + qr) * CNH + h) * CHD + nt * 16 + rsel] =
          __float2bfloat16(o[nt][j] * inv);
  }
}

extern "C" void kernel_launch(void* const* d_in, const int* in_sizes, int n_in,
                              void* d_out, int out_size, void* d_ws, size_t ws_size,
                              hipStream_t stream) {
  const float* x = (const float*)d_in[0];
  const int* mask = (const int*)d_in[1];
  const float* w_qkv = (const float*)d_in[2];
  const float* w_o = (const float*)d_in[3];
  float* out = (float*)d_out;

  char* ws = (char*)d_ws;
  size_t off = 0;
  auto alloc = [&](size_t bytes) {
    char* p = ws + off;
    off += (bytes + 255) & ~(size_t)255;
    return p;
  };
  const size_t M = (size_t)CB * CS; // 4096
  __hip_bfloat16* x_bf  = (__hip_bfloat16*)alloc(M * CH * 2);
  __hip_bfloat16* wqkvT = (__hip_bfloat16*)alloc((size_t)CTHD * CH * 2);
  __hip_bfloat16* woT   = (__hip_bfloat16*)alloc((size_t)CH * CH * 2);
  __hip_bfloat16* qkv   = (__hip_bfloat16*)alloc(M * CTHD * 2);
  __hip_bfloat16* Qb    = (__hip_bfloat16*)alloc((size_t)CB * CNH * CS * CHD * 2);
  __hip_bfloat16* Kb    = (__hip_bfloat16*)alloc((size_t)CB * CNKV * CS * CHD * 2);
  __hip_bfloat16* VTb   = (__hip_bfloat16*)alloc((size_t)CB * CNKV * CHD * CS * 2);
  __hip_bfloat16* attnb = (__hip_bfloat16*)alloc(M * CH * 2);

  conv_bf16<<<(int)(M * CH / 4 / 256), 256, 0, stream>>>(x, x_bf, (int)(M * CH));
  transpose_conv<<<(CTHD / 32) * (CH / 32), 256, 0, stream>>>(w_qkv, wqkvT, CH, CTHD);
  transpose_conv<<<(CH / 32) * (CH / 32), 256, 0, stream>>>(w_o, woT, CH, CH);
  gemm_bt<__hip_bfloat16><<<(int)(M / 128) * (CTHD / 128), 256, 0, stream>>>(
      x_bf, wqkvT, qkv, (int)M, CTHD, CH);
  rope_extract<<<(int)(M * 40 * 32 / 256), 256, 0, stream>>>(qkv, Qb, Kb);
  v_transpose<<<CB * CNKV * 32, 256, 0, stream>>>(qkv, VTb);
  attn_fa<<<CB * CNH * 32, 256, 0, stream>>>(Qb, Kb, VTb, mask, attnb);
  gemm_bt<float><<<(int)(M / 128) * (CH / 128), 256, 0, stream>>>(
      attnb, woT, out, (int)M, CH, CH);
}

// Round 2
// 437.030 us; speedup vs baseline: 1.4132x; 1.4132x over previous
//
#include <hip/hip_runtime.h>
#include <hip/hip_bf16.h>
#include <cstdint>
#include <cstddef>

typedef __attribute__((ext_vector_type(8))) short bf16x8;
typedef __attribute__((ext_vector_type(4))) float f32x4;

static constexpr int CB  = 2;
static constexpr int CS  = 2048;
static constexpr int CH  = 2048;
static constexpr int CNH = 32;
static constexpr int CNKV = 8;
static constexpr int CHD = 64;
static constexpr int CTHD = 3072; // (NH + 2*NKV)*HD

__device__ __forceinline__ void gload_lds16(const void* g, void* l) {
  __builtin_amdgcn_global_load_lds(
      (const __attribute__((address_space(1))) unsigned int*)g,
      (__attribute__((address_space(3))) unsigned int*)l, 16, 0, 0);
}

// ---------------- elementwise fp32 -> bf16 ----------------
__global__ void conv_bf16(const float* __restrict__ in, __hip_bfloat16* __restrict__ out, int n) {
  const int i = (blockIdx.x * 256 + threadIdx.x) * 4;
  if (i >= n) return;
  const float4 v = *(const float4*)(in + i);
  out[i]     = __float2bfloat16(v.x);
  out[i + 1] = __float2bfloat16(v.y);
  out[i + 2] = __float2bfloat16(v.z);
  out[i + 3] = __float2bfloat16(v.w);
}

// ---------------- tiled transpose + convert (fp32 RxC -> bf16 CxR) ----------------
__global__ __launch_bounds__(256) void transpose_conv(const float* __restrict__ in,
                                                      __hip_bfloat16* __restrict__ out,
                                                      int R, int Cc) {
  __shared__ float t[32][33];
  const int nbx = Cc >> 5;
  const int bx = blockIdx.x % nbx, by = blockIdx.x / nbx;
  const int c0 = bx << 5, r0 = by << 5;
  const int tx = threadIdx.x & 31, ty = threadIdx.x >> 5; // ty 0..7
#pragma unroll
  for (int j = 0; j < 32; j += 8)
    t[ty + j][tx] = in[(size_t)(r0 + ty + j) * Cc + c0 + tx];
  __syncthreads();
#pragma unroll
  for (int j = 0; j < 32; j += 8)
    out[(size_t)(c0 + ty + j) * R + r0 + tx] = __float2bfloat16(t[tx][ty + j]);
}

// ---------------- GEMM: C[MxN] = A[MxK] * Bt[NxK]^T  (m97-style 128x128 tile, XCD swizzle) ----------------
template <typename OutT>
__global__ __launch_bounds__(256) void gemm_bt(const __hip_bfloat16* __restrict__ A,
                                               const __hip_bfloat16* __restrict__ Bt,
                                               OutT* __restrict__ C, int M, int N, int K) {
  __shared__ __hip_bfloat16 As[128 * 32];
  __shared__ __hip_bfloat16 Bs[128 * 32];
  const int tid = threadIdx.x;
  const int lane = tid & 63;
  const int wave = tid >> 6;
  const int nTn = N >> 7;
  // XCD-aware bijective swizzle (grid %8 == 0 for all our launches)
  const int nwg = gridDim.x;
  const int wg = (blockIdx.x & 7) * (nwg >> 3) + (blockIdx.x >> 3);
  const int tm = wg / nTn, tn = wg % nTn;
  const size_t m0 = (size_t)tm * 128, n0 = (size_t)tn * 128;
  const __hip_bfloat16* Ag = A + m0 * K;
  const __hip_bfloat16* Bg = Bt + n0 * K;
  const int wr = wave >> 1, wc = wave & 1;
  const int rsel = lane & 15, k8 = (lane >> 4) << 3;

  f32x4 acc[4][4];
#pragma unroll
  for (int m = 0; m < 4; ++m)
#pragma unroll
    for (int n = 0; n < 4; ++n) acc[m][n] = (f32x4){0.f, 0.f, 0.f, 0.f};

  for (int k0 = 0; k0 < K; k0 += 32) {
    __syncthreads();
#pragma unroll
    for (int i = 0; i < 2; ++i) {
      const int c = i * 256 + tid;
      const int r = c >> 2, kq = (c & 3) << 3;
      gload_lds16(Ag + (size_t)r * K + k0 + kq, &As[(i * 256 + wave * 64) * 8]);
      gload_lds16(Bg + (size_t)r * K + k0 + kq, &Bs[(i * 256 + wave * 64) * 8]);
    }
    __syncthreads();
    bf16x8 af[4], bfr[4];
#pragma unroll
    for (int m = 0; m < 4; ++m)
      af[m] = *(const bf16x8*)&As[(wr * 64 + m * 16 + rsel) * 32 + k8];
#pragma unroll
    for (int n = 0; n < 4; ++n)
      bfr[n] = *(const bf16x8*)&Bs[(wc * 64 + n * 16 + rsel) * 32 + k8];
#pragma unroll
    for (int m = 0; m < 4; ++m)
#pragma unroll
      for (int n = 0; n < 4; ++n)
        acc[m][n] = __builtin_amdgcn_mfma_f32_16x16x32_bf16(af[m], bfr[n], acc[m][n], 0, 0, 0);
  }

  const int rowb = (lane >> 4) << 2;
#pragma unroll
  for (int m = 0; m < 4; ++m)
#pragma unroll
    for (int n = 0; n < 4; ++n) {
      const size_t r0 = m0 + wr * 64 + m * 16 + rowb;
      const size_t cc = n0 + wc * 64 + n * 16 + rsel;
#pragma unroll
      for (int j = 0; j < 4; ++j) {
        const float v = acc[m][n][j];
        if constexpr (sizeof(OutT) == 4)
          C[(r0 + j) * N + cc] = v;
        else
          C[(r0 + j) * N + cc] = __float2bfloat16(v);
      }
    }
}

// ---------------- RoPE + extract Q/K ----------------
__global__ void rope_extract(const __hip_bfloat16* __restrict__ qkv,
                             __hip_bfloat16* __restrict__ Q,
                             __hip_bfloat16* __restrict__ Kr) {
  const int idx = blockIdx.x * 256 + threadIdx.x;
  const int i = idx & 31;
  const int hs = (idx >> 5) % 40;     // 0..31 = Q heads, 32..39 = K heads
  const int r = idx / (40 * 32);      // b*S + s
  const int srow = r & (CS - 1);
  const int b = r >> 11;
  const float inv = exp2f(-(float)i * (13.287712379549449f / 32.0f)); // 10000^(-i/32)
  const float ang = (float)srow * inv;
  const float sn = sinf(ang), cs = cosf(ang);
  const int col = (hs < CNH) ? hs * CHD + 2 * i : CH + (hs - CNH) * CHD + 2 * i;
  const float t1 = __bfloat162float(qkv[(size_t)r * CTHD + col]);
  const float t2 = __bfloat162float(qkv[(size_t)r * CTHD + col + 1]);
  const float ev = t1 * cs - t2 * sn;
  const float ov = t1 * sn + t2 * cs;
  __hip_bfloat16* dst;
  if (hs < CNH)
    dst = Q + ((((size_t)b * CNH + hs) * CS + srow) * CHD + 2 * i);
  else
    dst = Kr + ((((size_t)b * CNKV + (hs - CNH)) * CS + srow) * CHD + 2 * i);
  dst[0] = __float2bfloat16(ev);
  dst[1] = __float2bfloat16(ov);
}

// ---------------- V extract + transpose: VT[b][kvh][d][s] ----------------
__global__ __launch_bounds__(256) void v_transpose(const __hip_bfloat16* __restrict__ qkv,
                                                   __hip_bfloat16* __restrict__ VT) {
  __shared__ __hip_bfloat16 t[64][72];
  const int bi = blockIdx.x;
  const int stile = bi & 31;
  const int kvh = (bi >> 5) & 7;
  const int b = bi >> 8;
  const int tx = threadIdx.x & 63;
  const int ty = threadIdx.x >> 6; // 0..3
  const int s0 = stile * 64;
#pragma unroll
  for (int j = 0; j < 16; ++j) {
    const int sl = ty * 16 + j;
    t[sl][tx] = qkv[(size_t)(b * CS + s0 + sl) * CTHD + (CH + CNKV * CHD) + kvh * CHD + tx];
  }
  __syncthreads();
#pragma unroll
  for (int j = 0; j < 16; ++j) {
    const int dl = ty * 16 + j;
    VT[(((size_t)b * CNKV + kvh) * CHD + dl) * CS + s0 + tx] = t[tx][dl];
  }
}

// ---------------- GQA causal flash attention ----------------
// grid 2048; decode: xcd=bid&7 owns kvh=xcd (K+V 1MB -> fits per-XCD L2),
// qt descends with dispatch order (heavy blocks first -> no tail).
// block 256 = 4 waves, each wave owns 16 q rows; K register-prefetched.
__global__ __launch_bounds__(256) void attn_fa(const __hip_bfloat16* __restrict__ Q,
                                               const __hip_bfloat16* __restrict__ Kr,
                                               const __hip_bfloat16* __restrict__ VT,
                                               const int* __restrict__ mask,
                                               __hip_bfloat16* __restrict__ O) {
  __shared__ __hip_bfloat16 Plds[4][16][72];
  const int xcd = blockIdx.x & 7;
  const int slot = blockIdx.x >> 3;
  const int qt = 31 - (slot >> 3);   // heavy-first
  const int grp = (slot >> 2) & 1;
  const int h4 = slot & 3;
  const int b = grp;
  const int kvh = xcd;
  const int h = kvh * 4 + h4;
  const int wave = threadIdx.x >> 6, lane = threadIdx.x & 63;
  const int q0 = qt * 64 + wave * 16;
  const int rsel = lane & 15, k8 = (lane >> 4) << 3;
  const int rowb = (lane >> 4) << 2;
  const __hip_bfloat16* Qp = Q + (((size_t)b * CNH + h) * CS + q0) * CHD;
  const __hip_bfloat16* Kp = Kr + ((size_t)b * CNKV + kvh) * CS * CHD;
  const __hip_bfloat16* Vp = VT + ((size_t)b * CNKV + kvh) * CHD * CS;
  const int* mp = mask + b * CS;
  __hip_bfloat16(*P)[72] = Plds[wave];

  bf16x8 qf[2];
  qf[0] = *(const bf16x8*)(Qp + rsel * CHD + k8);
  qf[1] = *(const bf16x8*)(Qp + rsel * CHD + 32 + k8);

  f32x4 o[4];
#pragma unroll
  for (int nt = 0; nt < 4; ++nt) o[nt] = (f32x4){0.f, 0.f, 0.f, 0.f};
  float mrun[4] = {-3e38f, -3e38f, -3e38f, -3e38f};
  float lrun[4] = {0.f, 0.f, 0.f, 0.f};

  const int nkb = qt + 1;

  auto loadK = [&](bf16x8(&kf)[8], int key0) {
#pragma unroll
    for (int kt = 0; kt < 4; ++kt) {
      const __hip_bfloat16* krow = Kp + (size_t)(key0 + kt * 16 + rsel) * CHD;
      kf[kt * 2]     = *(const bf16x8*)(krow + k8);
      kf[kt * 2 + 1] = *(const bf16x8*)(krow + 32 + k8);
    }
  };

  auto body = [&](bf16x8(&kc)[8], bf16x8(&kn)[8], int kb) {
    const int key0 = kb * 64;
    if (kb + 1 < nkb) loadK(kn, key0 + 64);  // prefetch next K tile into regs
    f32x4 st[4];
#pragma unroll
    for (int kt = 0; kt < 4; ++kt) {
      f32x4 s = (f32x4){0.f, 0.f, 0.f, 0.f};
      s = __builtin_amdgcn_mfma_f32_16x16x32_bf16(qf[0], kc[kt * 2], s, 0, 0, 0);
      s = __builtin_amdgcn_mfma_f32_16x16x32_bf16(qf[1], kc[kt * 2 + 1], s, 0, 0, 0);
      st[kt] = s;
    }
    // scale + causal + key mask
#pragma unroll
    for (int kt = 0; kt < 4; ++kt) {
      const int key = key0 + kt * 16 + rsel;
      const bool kvalid = mp[key] > 0;
#pragma unroll
      for (int j = 0; j < 4; ++j) {
        float sv = st[kt][j] * 0.125f;
        const int qr = q0 + rowb + j;
        if (key > qr || !kvalid) sv = -1e9f;
        st[kt][j] = sv;
      }
    }
    // online softmax stats (reduce across the 16 key-lanes)
    float al[4];
#pragma unroll
    for (int j = 0; j < 4; ++j) {
      float v = fmaxf(fmaxf(st[0][j], st[1][j]), fmaxf(st[2][j], st[3][j]));
#pragma unroll
      for (int d = 1; d < 16; d <<= 1) v = fmaxf(v, __shfl_xor(v, d));
      const float mn = fmaxf(mrun[j], v);
      al[j] = exp2f((mrun[j] - mn) * 1.44269504f);
      mrun[j] = mn;
    }
    float ps[4] = {0.f, 0.f, 0.f, 0.f};
#pragma unroll
    for (int kt = 0; kt < 4; ++kt)
#pragma unroll
      for (int j = 0; j < 4; ++j) {
        const float p = exp2f((st[kt][j] - mrun[j]) * 1.44269504f);
        st[kt][j] = p;
        ps[j] += p;
      }
#pragma unroll
    for (int j = 0; j < 4; ++j) {
      float v = ps[j];
#pragma unroll
      for (int d = 1; d < 16; d <<= 1) v += __shfl_xor(v, d);
      lrun[j] = lrun[j] * al[j] + v;
#pragma unroll
      for (int nt = 0; nt < 4; ++nt) o[nt][j] *= al[j];
    }
    // P (C/D layout) -> LDS -> A-fragment layout (wave-private buffer)
#pragma unroll
    for (int kt = 0; kt < 4; ++kt)
#pragma unroll
      for (int j = 0; j < 4; ++j)
        P[rowb + j][kt * 16 + rsel] = __float2bfloat16(st[kt][j]);
    const bf16x8 pa0 = *(const bf16x8*)&P[rsel][k8];
    const bf16x8 pa1 = *(const bf16x8*)&P[rsel][32 + k8];
#pragma unroll
    for (int nt = 0; nt < 4; ++nt) {
      const __hip_bfloat16* vrow = Vp + (size_t)(nt * 16 + rsel) * CS + key0;
      const bf16x8 vf0 = *(const bf16x8*)(vrow + k8);
      const bf16x8 vf1 = *(const bf16x8*)(vrow + 32 + k8);
      o[nt] = __builtin_amdgcn_mfma_f32_16x16x32_bf16(pa0, vf0, o[nt], 0, 0, 0);
      o[nt] = __builtin_amdgcn_mfma_f32_16x16x32_bf16(pa1, vf1, o[nt], 0, 0, 0);
    }
  };

  bf16x8 kA[8], kB[8];
  loadK(kA, 0);
  for (int kb = 0; kb < nkb; kb += 2) {
    body(kA, kB, kb);
    if (kb + 1 < nkb) body(kB, kA, kb + 1);
  }

#pragma unroll
  for (int j = 0; j < 4; ++j) {
    const int qr = q0 + rowb + j;
    const float qm = (mp[qr] > 0) ? 1.0f : 0.0f;
    const float inv = qm / fmaxf(lrun[j], 1e-20f);
#pragma unroll
    for (int nt = 0; nt < 4; ++nt)
      O[(((size_t)b * CS + qr) * CNH + h) * CHD + nt * 16 + rsel] =
          __float2bfloat16(o[nt][j] * inv);
  }
}

extern "C" void kernel_launch(void* const* d_in, const int* in_sizes, int n_in,
                              void* d_out, int out_size, void* d_ws, size_t ws_size,
                              hipStream_t stream) {
  const float* x = (const float*)d_in[0];
  const int* mask = (const int*)d_in[1];
  const float* w_qkv = (const float*)d_in[2];
  const float* w_o = (const float*)d_in[3];
  float* out = (float*)d_out;

  char* ws = (char*)d_ws;
  size_t off = 0;
  auto alloc = [&](size_t bytes) {
    char* p = ws + off;
    off += (bytes + 255) & ~(size_t)255;
    return p;
  };
  const size_t M = (size_t)CB * CS; // 4096
  __hip_bfloat16* x_bf  = (__hip_bfloat16*)alloc(M * CH * 2);
  __hip_bfloat16* wqkvT = (__hip_bfloat16*)alloc((size_t)CTHD * CH * 2);
  __hip_bfloat16* woT   = (__hip_bfloat16*)alloc((size_t)CH * CH * 2);
  __hip_bfloat16* qkv   = (__hip_bfloat16*)alloc(M * CTHD * 2);
  __hip_bfloat16* Qb    = (__hip_bfloat16*)alloc((size_t)CB * CNH * CS * CHD * 2);
  __hip_bfloat16* Kb    = (__hip_bfloat16*)alloc((size_t)CB * CNKV * CS * CHD * 2);
  __hip_bfloat16* VTb   = (__hip_bfloat16*)alloc((size_t)CB * CNKV * CHD * CS * 2);
  __hip_bfloat16* attnb = (__hip_bfloat16*)alloc(M * CH * 2);

  conv_bf16<<<(int)(M * CH / 4 / 256), 256, 0, stream>>>(x, x_bf, (int)(M * CH));
  transpose_conv<<<(CTHD / 32) * (CH / 32), 256, 0, stream>>>(w_qkv, wqkvT, CH, CTHD);
  transpose_conv<<<(CH / 32) * (CH / 32), 256, 0, stream>>>(w_o, woT, CH, CH);
  gemm_bt<__hip_bfloat16><<<(int)(M / 128) * (CTHD / 128), 256, 0, stream>>>(
      x_bf, wqkvT, qkv, (int)M, CTHD, CH);
  rope_extract<<<(int)(M * 40 * 32 / 256), 256, 0, stream>>>(qkv, Qb, Kb);
  v_transpose<<<CB * CNKV * 32, 256, 0, stream>>>(qkv, VTb);
  attn_fa<<<CB * CNH * 32, 256, 0, stream>>>(Qb, Kb, VTb, mask, attnb);
  gemm_bt<float><<<(int)(M / 128) * (CH / 128), 256, 0, stream>>>(
      attnb, woT, out, (int)M, CH, CH);
}

// Round 3
// 400.947 us; speedup vs baseline: 1.5404x; 1.0900x over previous
//
#include <hip/hip_runtime.h>
#include <hip/hip_bf16.h>
#include <cstdint>
#include <cstddef>

typedef __attribute__((ext_vector_type(8))) short bf16x8;
typedef __attribute__((ext_vector_type(4))) float f32x4;

static constexpr int CB  = 2;
static constexpr int CS  = 2048;
static constexpr int CH  = 2048;
static constexpr int CNH = 32;
static constexpr int CNKV = 8;
static constexpr int CHD = 64;
static constexpr int CTHD = 3072; // (NH + 2*NKV)*HD

__device__ __forceinline__ void gload_lds16(const void* g, void* l) {
  __builtin_amdgcn_global_load_lds(
      (const __attribute__((address_space(1))) unsigned int*)g,
      (__attribute__((address_space(3))) unsigned int*)l, 16, 0, 0);
}

__device__ __forceinline__ unsigned short bfbits(float f) {
  __hip_bfloat16 h = __float2bfloat16(f);
  return *(unsigned short*)&h;
}

// ---------------- elementwise fp32 -> bf16 ----------------
__global__ void conv_bf16(const float* __restrict__ in, __hip_bfloat16* __restrict__ out, int n) {
  const int i = (blockIdx.x * 256 + threadIdx.x) * 4;
  if (i >= n) return;
  const float4 v = *(const float4*)(in + i);
  out[i]     = __float2bfloat16(v.x);
  out[i + 1] = __float2bfloat16(v.y);
  out[i + 2] = __float2bfloat16(v.z);
  out[i + 3] = __float2bfloat16(v.w);
}

// ---------------- tiled transpose + convert (fp32 RxC -> bf16 CxR) ----------------
__global__ __launch_bounds__(256) void transpose_conv(const float* __restrict__ in,
                                                      __hip_bfloat16* __restrict__ out,
                                                      int R, int Cc) {
  __shared__ float t[32][33];
  const int nbx = Cc >> 5;
  const int bx = blockIdx.x % nbx, by = blockIdx.x / nbx;
  const int c0 = bx << 5, r0 = by << 5;
  const int tx = threadIdx.x & 31, ty = threadIdx.x >> 5; // ty 0..7
#pragma unroll
  for (int j = 0; j < 32; j += 8)
    t[ty + j][tx] = in[(size_t)(r0 + ty + j) * Cc + c0 + tx];
  __syncthreads();
#pragma unroll
  for (int j = 0; j < 32; j += 8)
    out[(size_t)(c0 + ty + j) * R + r0 + tx] = __float2bfloat16(t[tx][ty + j]);
}

// ---------------- GEMM: C[MxN] = A[MxK] * Bt[NxK]^T  (m97-style 128x128 tile, XCD swizzle) ----------------
template <typename OutT>
__global__ __launch_bounds__(256) void gemm_bt(const __hip_bfloat16* __restrict__ A,
                                               const __hip_bfloat16* __restrict__ Bt,
                                               OutT* __restrict__ C, int M, int N, int K) {
  __shared__ __hip_bfloat16 As[128 * 32];
  __shared__ __hip_bfloat16 Bs[128 * 32];
  const int tid = threadIdx.x;
  const int lane = tid & 63;
  const int wave = tid >> 6;
  const int nTn = N >> 7;
  const int nwg = gridDim.x;
  const int wg = (blockIdx.x & 7) * (nwg >> 3) + (blockIdx.x >> 3);
  const int tm = wg / nTn, tn = wg % nTn;
  const size_t m0 = (size_t)tm * 128, n0 = (size_t)tn * 128;
  const __hip_bfloat16* Ag = A + m0 * K;
  const __hip_bfloat16* Bg = Bt + n0 * K;
  const int wr = wave >> 1, wc = wave & 1;
  const int rsel = lane & 15, k8 = (lane >> 4) << 3;

  f32x4 acc[4][4];
#pragma unroll
  for (int m = 0; m < 4; ++m)
#pragma unroll
    for (int n = 0; n < 4; ++n) acc[m][n] = (f32x4){0.f, 0.f, 0.f, 0.f};

  for (int k0 = 0; k0 < K; k0 += 32) {
    __syncthreads();
#pragma unroll
    for (int i = 0; i < 2; ++i) {
      const int c = i * 256 + tid;
      const int r = c >> 2, kq = (c & 3) << 3;
      gload_lds16(Ag + (size_t)r * K + k0 + kq, &As[(i * 256 + wave * 64) * 8]);
      gload_lds16(Bg + (size_t)r * K + k0 + kq, &Bs[(i * 256 + wave * 64) * 8]);
    }
    __syncthreads();
    bf16x8 af[4], bfr[4];
#pragma unroll
    for (int m = 0; m < 4; ++m)
      af[m] = *(const bf16x8*)&As[(wr * 64 + m * 16 + rsel) * 32 + k8];
#pragma unroll
    for (int n = 0; n < 4; ++n)
      bfr[n] = *(const bf16x8*)&Bs[(wc * 64 + n * 16 + rsel) * 32 + k8];
#pragma unroll
    for (int m = 0; m < 4; ++m)
#pragma unroll
      for (int n = 0; n < 4; ++n)
        acc[m][n] = __builtin_amdgcn_mfma_f32_16x16x32_bf16(af[m], bfr[n], acc[m][n], 0, 0, 0);
  }

  const int rowb = (lane >> 4) << 2;
#pragma unroll
  for (int m = 0; m < 4; ++m)
#pragma unroll
    for (int n = 0; n < 4; ++n) {
      const size_t r0 = m0 + wr * 64 + m * 16 + rowb;
      const size_t cc = n0 + wc * 64 + n * 16 + rsel;
#pragma unroll
      for (int j = 0; j < 4; ++j) {
        const float v = acc[m][n][j];
        if constexpr (sizeof(OutT) == 4)
          C[(r0 + j) * N + cc] = v;
        else
          C[(r0 + j) * N + cc] = __float2bfloat16(v);
      }
    }
}

// ---------------- RoPE + extract Q/K ----------------
__global__ void rope_extract(const __hip_bfloat16* __restrict__ qkv,
                             __hip_bfloat16* __restrict__ Q,
                             __hip_bfloat16* __restrict__ Kr) {
  const int idx = blockIdx.x * 256 + threadIdx.x;
  const int i = idx & 31;
  const int hs = (idx >> 5) % 40;     // 0..31 = Q heads, 32..39 = K heads
  const int r = idx / (40 * 32);      // b*S + s
  const int srow = r & (CS - 1);
  const int b = r >> 11;
  const float inv = exp2f(-(float)i * (13.287712379549449f / 32.0f)); // 10000^(-i/32)
  const float ang = (float)srow * inv;
  const float sn = sinf(ang), cs = cosf(ang);
  const int col = (hs < CNH) ? hs * CHD + 2 * i : CH + (hs - CNH) * CHD + 2 * i;
  const float t1 = __bfloat162float(qkv[(size_t)r * CTHD + col]);
  const float t2 = __bfloat162float(qkv[(size_t)r * CTHD + col + 1]);
  const float ev = t1 * cs - t2 * sn;
  const float ov = t1 * sn + t2 * cs;
  __hip_bfloat16* dst;
  if (hs < CNH)
    dst = Q + ((((size_t)b * CNH + hs) * CS + srow) * CHD + 2 * i);
  else
    dst = Kr + ((((size_t)b * CNKV + (hs - CNH)) * CS + srow) * CHD + 2 * i);
  dst[0] = __float2bfloat16(ev);
  dst[1] = __float2bfloat16(ov);
}

// ---------------- V extract + transpose: VT[b][kvh][d][s] ----------------
__global__ __launch_bounds__(256) void v_transpose(const __hip_bfloat16* __restrict__ qkv,
                                                   __hip_bfloat16* __restrict__ VT) {
  __shared__ __hip_bfloat16 t[64][72];
  const int bi = blockIdx.x;
  const int stile = bi & 31;
  const int kvh = (bi >> 5) & 7;
  const int b = bi >> 8;
  const int tx = threadIdx.x & 63;
  const int ty = threadIdx.x >> 6; // 0..3
  const int s0 = stile * 64;
#pragma unroll
  for (int j = 0; j < 16; ++j) {
    const int sl = ty * 16 + j;
    t[sl][tx] = qkv[(size_t)(b * CS + s0 + sl) * CTHD + (CH + CNKV * CHD) + kvh * CHD + tx];
  }
  __syncthreads();
#pragma unroll
  for (int j = 0; j < 16; ++j) {
    const int dl = ty * 16 + j;
    VT[(((size_t)b * CNKV + kvh) * CHD + dl) * CS + s0 + tx] = t[tx][dl];
  }
}

// ---------------- GQA causal flash attention (swapped-operand MFMA) ----------------
// grid 2048; xcd=bid&7 owns kvh=xcd (K+V fits per-XCD L2); qt descends (heavy-first).
// block 256 = 4 waves x 16 q-rows. Swapped QK^T: lane owns one q-row's scores ->
// lane-local softmax (2 shfl per reduce). PV also swapped: O^T accum, scalar rescale.
__global__ __launch_bounds__(256) void attn_fa(const __hip_bfloat16* __restrict__ Q,
                                               const __hip_bfloat16* __restrict__ Kr,
                                               const __hip_bfloat16* __restrict__ VT,
                                               const int* __restrict__ mask,
                                               __hip_bfloat16* __restrict__ O) {
  __shared__ __hip_bfloat16 Plds[4][16][72];
  const int xcd = blockIdx.x & 7;
  const int slot = blockIdx.x >> 3;
  const int qt = 31 - (slot >> 3);   // heavy-first
  const int grp = (slot >> 2) & 1;
  const int h4 = slot & 3;
  const int b = grp;
  const int kvh = xcd;
  const int h = kvh * 4 + h4;
  const int wave = threadIdx.x >> 6, lane = threadIdx.x & 63;
  const int q0 = qt * 64 + wave * 16;
  const int rsel = lane & 15;        // this lane's q-row (and A-row selector)
  const int hi = lane >> 4;          // 0..3
  const int k8 = hi * 8;
  const int rowb = hi * 4;
  const int qr = q0 + rsel;
  const __hip_bfloat16* Qp = Q + (((size_t)b * CNH + h) * CS + q0) * CHD;
  const __hip_bfloat16* Kp = Kr + ((size_t)b * CNKV + kvh) * CS * CHD;
  const __hip_bfloat16* Vp = VT + ((size_t)b * CNKV + kvh) * CHD * CS;
  const int* mp = mask + b * CS;
  __hip_bfloat16(*P)[72] = Plds[wave];

  bf16x8 qf[2];
  qf[0] = *(const bf16x8*)(Qp + rsel * CHD + k8);
  qf[1] = *(const bf16x8*)(Qp + rsel * CHD + 32 + k8);

  f32x4 o[4]; // o[nt][j] = O^T[nt*16+rowb+j][qr]
#pragma unroll
  for (int nt = 0; nt < 4; ++nt) o[nt] = (f32x4){0.f, 0.f, 0.f, 0.f};
  float mrun = -3e38f, lrun = 0.f;

  const int nkb = qt + 1;

  auto loadK = [&](bf16x8(&kf)[8], int key0) {
#pragma unroll
    for (int kt = 0; kt < 4; ++kt) {
      const __hip_bfloat16* krow = Kp + (size_t)(key0 + kt * 16 + rsel) * CHD;
      kf[kt * 2]     = *(const bf16x8*)(krow + k8);
      kf[kt * 2 + 1] = *(const bf16x8*)(krow + 32 + k8);
    }
  };

  auto body = [&](bf16x8(&kc)[8], bf16x8(&kn)[8], int kb) {
    const int key0 = kb * 64;
    const bool last = (kb == nkb - 1);
    if (!last) loadK(kn, key0 + 64);  // register prefetch next K tile
    const unsigned long long kvbits = __ballot(mp[key0 + lane] > 0);
    // S^T = K * Q^T : lane holds S^T[key0+kt*16+rowb+j][qr]
    f32x4 st[4];
#pragma unroll
    for (int kt = 0; kt < 4; ++kt) {
      f32x4 s = (f32x4){0.f, 0.f, 0.f, 0.f};
      s = __builtin_amdgcn_mfma_f32_16x16x32_bf16(kc[kt * 2], qf[0], s, 0, 0, 0);
      s = __builtin_amdgcn_mfma_f32_16x16x32_bf16(kc[kt * 2 + 1], qf[1], s, 0, 0, 0);
      st[kt] = s;
    }
    if (kvbits == ~0ull && !last) {
#pragma unroll
      for (int kt = 0; kt < 4; ++kt)
#pragma unroll
        for (int j = 0; j < 4; ++j) st[kt][j] *= 0.125f;
    } else {
#pragma unroll
      for (int kt = 0; kt < 4; ++kt)
#pragma unroll
        for (int j = 0; j < 4; ++j) {
          const int idx = kt * 16 + rowb + j;
          const bool bad = !((kvbits >> idx) & 1ull) || (last && key0 + idx > qr);
          st[kt][j] = bad ? -1e9f : st[kt][j] * 0.125f;
        }
    }
    // lane-local softmax over this lane's 16 keys, then cross-hi combine (2 shfl)
    float pmax = st[0][0];
#pragma unroll
    for (int kt = 0; kt < 4; ++kt)
#pragma unroll
      for (int j = 0; j < 4; ++j) pmax = fmaxf(pmax, st[kt][j]);
    pmax = fmaxf(pmax, __shfl_xor(pmax, 16));
    pmax = fmaxf(pmax, __shfl_xor(pmax, 32));
    const float mn = fmaxf(mrun, pmax);
    const float al = exp2f((mrun - mn) * 1.44269504f);
    mrun = mn;
    float ps = 0.f;
#pragma unroll
    for (int kt = 0; kt < 4; ++kt)
#pragma unroll
      for (int j = 0; j < 4; ++j) {
        const float p = exp2f((st[kt][j] - mn) * 1.44269504f);
        st[kt][j] = p;
        ps += p;
      }
    ps += __shfl_xor(ps, 16);
    ps += __shfl_xor(ps, 32);
    lrun = lrun * al + ps;
#pragma unroll
    for (int nt = 0; nt < 4; ++nt)
#pragma unroll
      for (int j = 0; j < 4; ++j) o[nt][j] *= al;
    // P^T -> LDS as P[q][key] (8B packed writes), read back as B-fragments
#pragma unroll
    for (int kt = 0; kt < 4; ++kt) {
      ushort4 pk;
      pk.x = bfbits(st[kt][0]);
      pk.y = bfbits(st[kt][1]);
      pk.z = bfbits(st[kt][2]);
      pk.w = bfbits(st[kt][3]);
      *(ushort4*)&P[rsel][kt * 16 + rowb] = pk;
    }
    const bf16x8 pb0 = *(const bf16x8*)&P[rsel][k8];
    const bf16x8 pb1 = *(const bf16x8*)&P[rsel][32 + k8];
    // O^T += V^T * P^T
#pragma unroll
    for (int nt = 0; nt < 4; ++nt) {
      const __hip_bfloat16* vrow = Vp + (size_t)(nt * 16 + rsel) * CS + key0;
      const bf16x8 vf0 = *(const bf16x8*)(vrow + k8);
      const bf16x8 vf1 = *(const bf16x8*)(vrow + 32 + k8);
      o[nt] = __builtin_amdgcn_mfma_f32_16x16x32_bf16(vf0, pb0, o[nt], 0, 0, 0);
      o[nt] = __builtin_amdgcn_mfma_f32_16x16x32_bf16(vf1, pb1, o[nt], 0, 0, 0);
    }
  };

  bf16x8 kA[8], kB[8];
  loadK(kA, 0);
  for (int kb = 0; kb < nkb; kb += 2) {
    body(kA, kB, kb);
    if (kb + 1 < nkb) body(kB, kA, kb + 1);
  }

  const float qm = (mp[qr] > 0) ? 1.0f : 0.0f;
  const float inv = qm / fmaxf(lrun, 1e-20f);
  __hip_bfloat16* Orow = O + (((size_t)b * CS + qr) * CNH + h) * CHD;
#pragma unroll
  for (int nt = 0; nt < 4; ++nt) {
    ushort4 ok;
    ok.x = bfbits(o[nt][0] * inv);
    ok.y = bfbits(o[nt][1] * inv);
    ok.z = bfbits(o[nt][2] * inv);
    ok.w = bfbits(o[nt][3] * inv);
    *(ushort4*)(Orow + nt * 16 + rowb) = ok;
  }
}

extern "C" void kernel_launch(void* const* d_in, const int* in_sizes, int n_in,
                              void* d_out, int out_size, void* d_ws, size_t ws_size,
                              hipStream_t stream) {
  const float* x = (const float*)d_in[0];
  const int* mask = (const int*)d_in[1];
  const float* w_qkv = (const float*)d_in[2];
  const float* w_o = (const float*)d_in[3];
  float* out = (float*)d_out;

  char* ws = (char*)d_ws;
  size_t off = 0;
  auto alloc = [&](size_t bytes) {
    char* p = ws + off;
    off += (bytes + 255) & ~(size_t)255;
    return p;
  };
  const size_t M = (size_t)CB * CS; // 4096
  __hip_bfloat16* x_bf  = (__hip_bfloat16*)alloc(M * CH * 2);
  __hip_bfloat16* wqkvT = (__hip_bfloat16*)alloc((size_t)CTHD * CH * 2);
  __hip_bfloat16* woT   = (__hip_bfloat16*)alloc((size_t)CH * CH * 2);
  __hip_bfloat16* qkv   = (__hip_bfloat16*)alloc(M * CTHD * 2);
  __hip_bfloat16* Qb    = (__hip_bfloat16*)alloc((size_t)CB * CNH * CS * CHD * 2);
  __hip_bfloat16* Kb    = (__hip_bfloat16*)alloc((size_t)CB * CNKV * CS * CHD * 2);
  __hip_bfloat16* VTb   = (__hip_bfloat16*)alloc((size_t)CB * CNKV * CHD * CS * 2);
  __hip_bfloat16* attnb = (__hip_bfloat16*)alloc(M * CH * 2);

  conv_bf16<<<(int)(M * CH / 4 / 256), 256, 0, stream>>>(x, x_bf, (int)(M * CH));
  transpose_conv<<<(CTHD / 32) * (CH / 32), 256, 0, stream>>>(w_qkv, wqkvT, CH, CTHD);
  transpose_conv<<<(CH / 32) * (CH / 32), 256, 0, stream>>>(w_o, woT, CH, CH);
  gemm_bt<__hip_bfloat16><<<(int)(M / 128) * (CTHD / 128), 256, 0, stream>>>(
      x_bf, wqkvT, qkv, (int)M, CTHD, CH);
  rope_extract<<<(int)(M * 40 * 32 / 256), 256, 0, stream>>>(qkv, Qb, Kb);
  v_transpose<<<CB * CNKV * 32, 256, 0, stream>>>(qkv, VTb);
  attn_fa<<<CB * CNH * 32, 256, 0, stream>>>(Qb, Kb, VTb, mask, attnb);
  gemm_bt<float><<<(int)(M / 128) * (CH / 128), 256, 0, stream>>>(
      attnb, woT, out, (int)M, CH, CH);
}

// Round 4
// 398.511 us; speedup vs baseline: 1.5498x; 1.0061x over previous
//
#include <hip/hip_runtime.h>
#include <hip/hip_bf16.h>
#include <cstdint>
#include <cstddef>

typedef __attribute__((ext_vector_type(8))) short bf16x8;
typedef __attribute__((ext_vector_type(4))) float f32x4;

static constexpr int CB  = 2;
static constexpr int CS  = 2048;
static constexpr int CH  = 2048;
static constexpr int CNH = 32;
static constexpr int CNKV = 8;
static constexpr int CHD = 64;
static constexpr int CTHD = 3072; // (NH + 2*NKV)*HD

__device__ __forceinline__ void gload_lds16(const void* g, void* l) {
  __builtin_amdgcn_global_load_lds(
      (const __attribute__((address_space(1))) unsigned int*)g,
      (__attribute__((address_space(3))) unsigned int*)l, 16, 0, 0);
}

__device__ __forceinline__ unsigned short bfbits(float f) {
  __hip_bfloat16 h = __float2bfloat16(f);
  return *(unsigned short*)&h;
}

// ---------------- elementwise fp32 -> bf16 ----------------
__global__ void conv_bf16(const float* __restrict__ in, __hip_bfloat16* __restrict__ out, int n) {
  const int i = (blockIdx.x * 256 + threadIdx.x) * 4;
  if (i >= n) return;
  const float4 v = *(const float4*)(in + i);
  out[i]     = __float2bfloat16(v.x);
  out[i + 1] = __float2bfloat16(v.y);
  out[i + 2] = __float2bfloat16(v.z);
  out[i + 3] = __float2bfloat16(v.w);
}

// ---------------- tiled transpose + convert (fp32 RxC -> bf16 CxR) ----------------
__global__ __launch_bounds__(256) void transpose_conv(const float* __restrict__ in,
                                                      __hip_bfloat16* __restrict__ out,
                                                      int R, int Cc) {
  __shared__ float t[32][33];
  const int nbx = Cc >> 5;
  const int bx = blockIdx.x % nbx, by = blockIdx.x / nbx;
  const int c0 = bx << 5, r0 = by << 5;
  const int tx = threadIdx.x & 31, ty = threadIdx.x >> 5; // ty 0..7
#pragma unroll
  for (int j = 0; j < 32; j += 8)
    t[ty + j][tx] = in[(size_t)(r0 + ty + j) * Cc + c0 + tx];
  __syncthreads();
#pragma unroll
  for (int j = 0; j < 32; j += 8)
    out[(size_t)(c0 + ty + j) * R + r0 + tx] = __float2bfloat16(t[tx][ty + j]);
}

// ---------------- GEMM: C[MxN] = A[MxK] * Bt[NxK]^T  (m97-style 128x128 tile, XCD swizzle) ----------------
template <typename OutT>
__global__ __launch_bounds__(256) void gemm_bt(const __hip_bfloat16* __restrict__ A,
                                               const __hip_bfloat16* __restrict__ Bt,
                                               OutT* __restrict__ C, int M, int N, int K) {
  __shared__ __hip_bfloat16 As[128 * 32];
  __shared__ __hip_bfloat16 Bs[128 * 32];
  const int tid = threadIdx.x;
  const int lane = tid & 63;
  const int wave = tid >> 6;
  const int nTn = N >> 7;
  const int nwg = gridDim.x;
  const int wg = (blockIdx.x & 7) * (nwg >> 3) + (blockIdx.x >> 3);
  const int tm = wg / nTn, tn = wg % nTn;
  const size_t m0 = (size_t)tm * 128, n0 = (size_t)tn * 128;
  const __hip_bfloat16* Ag = A + m0 * K;
  const __hip_bfloat16* Bg = Bt + n0 * K;
  const int wr = wave >> 1, wc = wave & 1;
  const int rsel = lane & 15, k8 = (lane >> 4) << 3;

  f32x4 acc[4][4];
#pragma unroll
  for (int m = 0; m < 4; ++m)
#pragma unroll
    for (int n = 0; n < 4; ++n) acc[m][n] = (f32x4){0.f, 0.f, 0.f, 0.f};

  for (int k0 = 0; k0 < K; k0 += 32) {
    __syncthreads();
#pragma unroll
    for (int i = 0; i < 2; ++i) {
      const int c = i * 256 + tid;
      const int r = c >> 2, kq = (c & 3) << 3;
      gload_lds16(Ag + (size_t)r * K + k0 + kq, &As[(i * 256 + wave * 64) * 8]);
      gload_lds16(Bg + (size_t)r * K + k0 + kq, &Bs[(i * 256 + wave * 64) * 8]);
    }
    __syncthreads();
    bf16x8 af[4], bfr[4];
#pragma unroll
    for (int m = 0; m < 4; ++m)
      af[m] = *(const bf16x8*)&As[(wr * 64 + m * 16 + rsel) * 32 + k8];
#pragma unroll
    for (int n = 0; n < 4; ++n)
      bfr[n] = *(const bf16x8*)&Bs[(wc * 64 + n * 16 + rsel) * 32 + k8];
#pragma unroll
    for (int m = 0; m < 4; ++m)
#pragma unroll
      for (int n = 0; n < 4; ++n)
        acc[m][n] = __builtin_amdgcn_mfma_f32_16x16x32_bf16(af[m], bfr[n], acc[m][n], 0, 0, 0);
  }

  const int rowb = (lane >> 4) << 2;
#pragma unroll
  for (int m = 0; m < 4; ++m)
#pragma unroll
    for (int n = 0; n < 4; ++n) {
      const size_t r0 = m0 + wr * 64 + m * 16 + rowb;
      const size_t cc = n0 + wc * 64 + n * 16 + rsel;
#pragma unroll
      for (int j = 0; j < 4; ++j) {
        const float v = acc[m][n][j];
        if constexpr (sizeof(OutT) == 4)
          C[(r0 + j) * N + cc] = v;
        else
          C[(r0 + j) * N + cc] = __float2bfloat16(v);
      }
    }
}

// ---------------- RoPE + extract Q/K ----------------
__global__ void rope_extract(const __hip_bfloat16* __restrict__ qkv,
                             __hip_bfloat16* __restrict__ Q,
                             __hip_bfloat16* __restrict__ Kr) {
  const int idx = blockIdx.x * 256 + threadIdx.x;
  const int i = idx & 31;
  const int hs = (idx >> 5) % 40;     // 0..31 = Q heads, 32..39 = K heads
  const int r = idx / (40 * 32);      // b*S + s
  const int srow = r & (CS - 1);
  const int b = r >> 11;
  const float inv = exp2f(-(float)i * (13.287712379549449f / 32.0f)); // 10000^(-i/32)
  const float ang = (float)srow * inv;
  const float sn = sinf(ang), cs = cosf(ang);
  const int col = (hs < CNH) ? hs * CHD + 2 * i : CH + (hs - CNH) * CHD + 2 * i;
  const float t1 = __bfloat162float(qkv[(size_t)r * CTHD + col]);
  const float t2 = __bfloat162float(qkv[(size_t)r * CTHD + col + 1]);
  const float ev = t1 * cs - t2 * sn;
  const float ov = t1 * sn + t2 * cs;
  __hip_bfloat16* dst;
  if (hs < CNH)
    dst = Q + ((((size_t)b * CNH + hs) * CS + srow) * CHD + 2 * i);
  else
    dst = Kr + ((((size_t)b * CNKV + (hs - CNH)) * CS + srow) * CHD + 2 * i);
  dst[0] = __float2bfloat16(ev);
  dst[1] = __float2bfloat16(ov);
}

// ---------------- V extract + transpose: VT[b][kvh][d][s] ----------------
__global__ __launch_bounds__(256) void v_transpose(const __hip_bfloat16* __restrict__ qkv,
                                                   __hip_bfloat16* __restrict__ VT) {
  __shared__ __hip_bfloat16 t[64][72];
  const int bi = blockIdx.x;
  const int stile = bi & 31;
  const int kvh = (bi >> 5) & 7;
  const int b = bi >> 8;
  const int tx = threadIdx.x & 63;
  const int ty = threadIdx.x >> 6; // 0..3
  const int s0 = stile * 64;
#pragma unroll
  for (int j = 0; j < 16; ++j) {
    const int sl = ty * 16 + j;
    t[sl][tx] = qkv[(size_t)(b * CS + s0 + sl) * CTHD + (CH + CNKV * CHD) + kvh * CHD + tx];
  }
  __syncthreads();
#pragma unroll
  for (int j = 0; j < 16; ++j) {
    const int dl = ty * 16 + j;
    VT[(((size_t)b * CNKV + kvh) * CHD + dl) * CS + s0 + tx] = t[tx][dl];
  }
}

// ---------------- GQA causal flash attention (swapped MFMA, 1-wave blocks) ----------------
// grid 8192 one-wave blocks: xcd=bid&7 owns kvh=xcd; qw descends (heavy-first, backfill-
// friendly). Wave owns 16 q-rows; lane-local softmax (2 shfl); K reg-double-buffered;
// mask prefetched one tile ahead; V issued before softmax so its latency hides.
__global__ __launch_bounds__(64) void attn_fa(const __hip_bfloat16* __restrict__ Q,
                                              const __hip_bfloat16* __restrict__ Kr,
                                              const __hip_bfloat16* __restrict__ VT,
                                              const int* __restrict__ mask,
                                              __hip_bfloat16* __restrict__ O) {
  __shared__ __hip_bfloat16 P[16][72];
  const int xcd = blockIdx.x & 7;
  const int slot = blockIdx.x >> 3;      // 0..1023
  const int qw = 127 - (slot >> 3);      // heavy-first: big key-ranges dispatch first
  const int b = (slot >> 2) & 1;
  const int h4 = slot & 3;
  const int kvh = xcd;
  const int h = kvh * 4 + h4;
  const int lane = threadIdx.x;
  const int q0 = qw * 16;
  const int rsel = lane & 15;            // this lane's q-row
  const int hi = lane >> 4;              // 0..3
  const int k8 = hi * 8;
  const int rowb = hi * 4;
  const int qr = q0 + rsel;
  const __hip_bfloat16* Qp = Q + (((size_t)b * CNH + h) * CS + q0) * CHD;
  const __hip_bfloat16* Kp = Kr + ((size_t)b * CNKV + kvh) * CS * CHD;
  const __hip_bfloat16* Vp = VT + ((size_t)b * CNKV + kvh) * CHD * CS;
  const int* mp = mask + b * CS;

  bf16x8 qf[2];
  qf[0] = *(const bf16x8*)(Qp + rsel * CHD + k8);
  qf[1] = *(const bf16x8*)(Qp + rsel * CHD + 32 + k8);

  f32x4 o[4]; // o[nt][j] = O^T[nt*16+rowb+j][qr]
#pragma unroll
  for (int nt = 0; nt < 4; ++nt) o[nt] = (f32x4){0.f, 0.f, 0.f, 0.f};
  float mrun = -3e38f, lrun = 0.f;

  const int nkb = (qw >> 2) + 1;  // keys 0 .. nkb*64-1 cover q-rows q0..q0+15

  auto loadK = [&](bf16x8(&kf)[8], int key0) {
#pragma unroll
    for (int kt = 0; kt < 4; ++kt) {
      const __hip_bfloat16* krow = Kp + (size_t)(key0 + kt * 16 + rsel) * CHD;
      kf[kt * 2]     = *(const bf16x8*)(krow + k8);
      kf[kt * 2 + 1] = *(const bf16x8*)(krow + 32 + k8);
    }
  };

  int mcur, mnext;
  auto body = [&](bf16x8(&kc)[8], bf16x8(&kn)[8], int kb) {
    const int key0 = kb * 64;
    const bool last = (kb == nkb - 1);
    if (!last) {
      loadK(kn, key0 + 64);               // register prefetch next K tile
      mnext = mp[key0 + 64 + lane];       // prefetch next mask word (off-chain)
    }
    const unsigned long long kvbits = __ballot(mcur > 0);
    // S^T = K * Q^T : lane holds S^T[key0+kt*16+rowb+j][qr]
    f32x4 st[4];
#pragma unroll
    for (int kt = 0; kt < 4; ++kt) {
      f32x4 s = (f32x4){0.f, 0.f, 0.f, 0.f};
      s = __builtin_amdgcn_mfma_f32_16x16x32_bf16(kc[kt * 2], qf[0], s, 0, 0, 0);
      s = __builtin_amdgcn_mfma_f32_16x16x32_bf16(kc[kt * 2 + 1], qf[1], s, 0, 0, 0);
      st[kt] = s;
    }
    // issue V loads NOW; consumed only after softmax -> latency hides under VALU
    bf16x8 vf[8];
#pragma unroll
    for (int nt = 0; nt < 4; ++nt) {
      const __hip_bfloat16* vrow = Vp + (size_t)(nt * 16 + rsel) * CS + key0;
      vf[nt * 2]     = *(const bf16x8*)(vrow + k8);
      vf[nt * 2 + 1] = *(const bf16x8*)(vrow + 32 + k8);
    }
    if (kvbits == ~0ull && !last) {
#pragma unroll
      for (int kt = 0; kt < 4; ++kt)
#pragma unroll
        for (int j = 0; j < 4; ++j) st[kt][j] *= 0.125f;
    } else {
#pragma unroll
      for (int kt = 0; kt < 4; ++kt)
#pragma unroll
        for (int j = 0; j < 4; ++j) {
          const int idx = kt * 16 + rowb + j;
          const bool bad = !((kvbits >> idx) & 1ull) || (last && key0 + idx > qr);
          st[kt][j] = bad ? -1e9f : st[kt][j] * 0.125f;
        }
    }
    // lane-local softmax over 16 keys, cross-hi combine via 2 shfl
    float pmax = st[0][0];
#pragma unroll
    for (int kt = 0; kt < 4; ++kt)
#pragma unroll
      for (int j = 0; j < 4; ++j) pmax = fmaxf(pmax, st[kt][j]);
    pmax = fmaxf(pmax, __shfl_xor(pmax, 16));
    pmax = fmaxf(pmax, __shfl_xor(pmax, 32));
    const float mn = fmaxf(mrun, pmax);
    const float al = exp2f((mrun - mn) * 1.44269504f);
    mrun = mn;
    float ps = 0.f;
#pragma unroll
    for (int kt = 0; kt < 4; ++kt)
#pragma unroll
      for (int j = 0; j < 4; ++j) {
        const float p = exp2f((st[kt][j] - mn) * 1.44269504f);
        st[kt][j] = p;
        ps += p;
      }
    ps += __shfl_xor(ps, 16);
    ps += __shfl_xor(ps, 32);
    lrun = lrun * al + ps;
#pragma unroll
    for (int nt = 0; nt < 4; ++nt)
#pragma unroll
      for (int j = 0; j < 4; ++j) o[nt][j] *= al;
    // P^T -> LDS as P[q][key] (8B packed writes), read back as B-fragments
#pragma unroll
    for (int kt = 0; kt < 4; ++kt) {
      ushort4 pk;
      pk.x = bfbits(st[kt][0]);
      pk.y = bfbits(st[kt][1]);
      pk.z = bfbits(st[kt][2]);
      pk.w = bfbits(st[kt][3]);
      *(ushort4*)&P[rsel][kt * 16 + rowb] = pk;
    }
    const bf16x8 pb0 = *(const bf16x8*)&P[rsel][k8];
    const bf16x8 pb1 = *(const bf16x8*)&P[rsel][32 + k8];
    // O^T += V^T * P^T
#pragma unroll
    for (int nt = 0; nt < 4; ++nt) {
      o[nt] = __builtin_amdgcn_mfma_f32_16x16x32_bf16(vf[nt * 2], pb0, o[nt], 0, 0, 0);
      o[nt] = __builtin_amdgcn_mfma_f32_16x16x32_bf16(vf[nt * 2 + 1], pb1, o[nt], 0, 0, 0);
    }
  };

  bf16x8 kA[8], kB[8];
  loadK(kA, 0);
  mcur = mp[lane];
  for (int kb = 0; kb < nkb; kb += 2) {
    body(kA, kB, kb);
    mcur = mnext;
    if (kb + 1 < nkb) {
      body(kB, kA, kb + 1);
      mcur = mnext;
    }
  }

  const float qm = (mp[qr] > 0) ? 1.0f : 0.0f;
  const float inv = qm / fmaxf(lrun, 1e-20f);
  __hip_bfloat16* Orow = O + (((size_t)b * CS + qr) * CNH + h) * CHD;
#pragma unroll
  for (int nt = 0; nt < 4; ++nt) {
    ushort4 ok;
    ok.x = bfbits(o[nt][0] * inv);
    ok.y = bfbits(o[nt][1] * inv);
    ok.z = bfbits(o[nt][2] * inv);
    ok.w = bfbits(o[nt][3] * inv);
    *(ushort4*)(Orow + nt * 16 + rowb) = ok;
  }
}

extern "C" void kernel_launch(void* const* d_in, const int* in_sizes, int n_in,
                              void* d_out, int out_size, void* d_ws, size_t ws_size,
                              hipStream_t stream) {
  const float* x = (const float*)d_in[0];
  const int* mask = (const int*)d_in[1];
  const float* w_qkv = (const float*)d_in[2];
  const float* w_o = (const float*)d_in[3];
  float* out = (float*)d_out;

  char* ws = (char*)d_ws;
  size_t off = 0;
  auto alloc = [&](size_t bytes) {
    char* p = ws + off;
    off += (bytes + 255) & ~(size_t)255;
    return p;
  };
  const size_t M = (size_t)CB * CS; // 4096
  __hip_bfloat16* x_bf  = (__hip_bfloat16*)alloc(M * CH * 2);
  __hip_bfloat16* wqkvT = (__hip_bfloat16*)alloc((size_t)CTHD * CH * 2);
  __hip_bfloat16* woT   = (__hip_bfloat16*)alloc((size_t)CH * CH * 2);
  __hip_bfloat16* qkv   = (__hip_bfloat16*)alloc(M * CTHD * 2);
  __hip_bfloat16* Qb    = (__hip_bfloat16*)alloc((size_t)CB * CNH * CS * CHD * 2);
  __hip_bfloat16* Kb    = (__hip_bfloat16*)alloc((size_t)CB * CNKV * CS * CHD * 2);
  __hip_bfloat16* VTb   = (__hip_bfloat16*)alloc((size_t)CB * CNKV * CHD * CS * 2);
  __hip_bfloat16* attnb = (__hip_bfloat16*)alloc(M * CH * 2);

  conv_bf16<<<(int)(M * CH / 4 / 256), 256, 0, stream>>>(x, x_bf, (int)(M * CH));
  transpose_conv<<<(CTHD / 32) * (CH / 32), 256, 0, stream>>>(w_qkv, wqkvT, CH, CTHD);
  transpose_conv<<<(CH / 32) * (CH / 32), 256, 0, stream>>>(w_o, woT, CH, CH);
  gemm_bt<__hip_bfloat16><<<(int)(M / 128) * (CTHD / 128), 256, 0, stream>>>(
      x_bf, wqkvT, qkv, (int)M, CTHD, CH);
  rope_extract<<<(int)(M * 40 * 32 / 256), 256, 0, stream>>>(qkv, Qb, Kb);
  v_transpose<<<CB * CNKV * 32, 256, 0, stream>>>(qkv, VTb);
  attn_fa<<<CB * CNH * 4 * 128 / 4, 64, 0, stream>>>(Qb, Kb, VTb, mask, attnb);
  gemm_bt<float><<<(int)(M / 128) * (CH / 128), 256, 0, stream>>>(
      attnb, woT, out, (int)M, CH, CH);
}

// Round 5
// 265.573 us; speedup vs baseline: 2.3256x; 1.5006x over previous
//
#include <hip/hip_runtime.h>
#include <hip/hip_bf16.h>
#include <cstdint>
#include <cstddef>

typedef __attribute__((ext_vector_type(8))) short bf16x8;
typedef __attribute__((ext_vector_type(4))) float f32x4;

static constexpr int CB  = 2;
static constexpr int CS  = 2048;
static constexpr int CH  = 2048;
static constexpr int CNH = 32;
static constexpr int CNKV = 8;
static constexpr int CHD = 64;
static constexpr int CTHD = 3072; // (NH + 2*NKV)*HD

__device__ __forceinline__ void gload_lds16(const void* g, void* l) {
  __builtin_amdgcn_global_load_lds(
      (const __attribute__((address_space(1))) unsigned int*)g,
      (__attribute__((address_space(3))) unsigned int*)l, 16, 0, 0);
}

__device__ __forceinline__ unsigned short bfbits(float f) {
  __hip_bfloat16 h = __float2bfloat16(f);
  return *(unsigned short*)&h;
}

// ---------------- elementwise fp32 -> bf16 ----------------
__global__ void conv_bf16(const float* __restrict__ in, __hip_bfloat16* __restrict__ out, int n) {
  const int i = (blockIdx.x * 256 + threadIdx.x) * 4;
  if (i >= n) return;
  const float4 v = *(const float4*)(in + i);
  out[i]     = __float2bfloat16(v.x);
  out[i + 1] = __float2bfloat16(v.y);
  out[i + 2] = __float2bfloat16(v.z);
  out[i + 3] = __float2bfloat16(v.w);
}

// ---------------- tiled transpose + convert (fp32 RxC -> bf16 CxR) ----------------
__global__ __launch_bounds__(256) void transpose_conv(const float* __restrict__ in,
                                                      __hip_bfloat16* __restrict__ out,
                                                      int R, int Cc) {
  __shared__ float t[32][33];
  const int nbx = Cc >> 5;
  const int bx = blockIdx.x % nbx, by = blockIdx.x / nbx;
  const int c0 = bx << 5, r0 = by << 5;
  const int tx = threadIdx.x & 31, ty = threadIdx.x >> 5; // ty 0..7
#pragma unroll
  for (int j = 0; j < 32; j += 8)
    t[ty + j][tx] = in[(size_t)(r0 + ty + j) * Cc + c0 + tx];
  __syncthreads();
#pragma unroll
  for (int j = 0; j < 32; j += 8)
    out[(size_t)(c0 + ty + j) * R + r0 + tx] = __float2bfloat16(t[tx][ty + j]);
}

// ---------------- GEMM: C[MxN] = A[MxK] * Bt[NxK]^T  (m97-style 128x128 tile, XCD swizzle) ----------------
template <typename OutT>
__global__ __launch_bounds__(256) void gemm_bt(const __hip_bfloat16* __restrict__ A,
                                               const __hip_bfloat16* __restrict__ Bt,
                                               OutT* __restrict__ C, int M, int N, int K) {
  __shared__ __hip_bfloat16 As[128 * 32];
  __shared__ __hip_bfloat16 Bs[128 * 32];
  const int tid = threadIdx.x;
  const int lane = tid & 63;
  const int wave = tid >> 6;
  const int nTn = N >> 7;
  const int nwg = gridDim.x;
  const int wg = (blockIdx.x & 7) * (nwg >> 3) + (blockIdx.x >> 3);
  const int tm = wg / nTn, tn = wg % nTn;
  const size_t m0 = (size_t)tm * 128, n0 = (size_t)tn * 128;
  const __hip_bfloat16* Ag = A + m0 * K;
  const __hip_bfloat16* Bg = Bt + n0 * K;
  const int wr = wave >> 1, wc = wave & 1;
  const int rsel = lane & 15, k8 = (lane >> 4) << 3;

  f32x4 acc[4][4];
#pragma unroll
  for (int m = 0; m < 4; ++m)
#pragma unroll
    for (int n = 0; n < 4; ++n) acc[m][n] = (f32x4){0.f, 0.f, 0.f, 0.f};

  for (int k0 = 0; k0 < K; k0 += 32) {
    __syncthreads();
#pragma unroll
    for (int i = 0; i < 2; ++i) {
      const int c = i * 256 + tid;
      const int r = c >> 2, kq = (c & 3) << 3;
      gload_lds16(Ag + (size_t)r * K + k0 + kq, &As[(i * 256 + wave * 64) * 8]);
      gload_lds16(Bg + (size_t)r * K + k0 + kq, &Bs[(i * 256 + wave * 64) * 8]);
    }
    __syncthreads();
    bf16x8 af[4], bfr[4];
#pragma unroll
    for (int m = 0; m < 4; ++m)
      af[m] = *(const bf16x8*)&As[(wr * 64 + m * 16 + rsel) * 32 + k8];
#pragma unroll
    for (int n = 0; n < 4; ++n)
      bfr[n] = *(const bf16x8*)&Bs[(wc * 64 + n * 16 + rsel) * 32 + k8];
#pragma unroll
    for (int m = 0; m < 4; ++m)
#pragma unroll
      for (int n = 0; n < 4; ++n)
        acc[m][n] = __builtin_amdgcn_mfma_f32_16x16x32_bf16(af[m], bfr[n], acc[m][n], 0, 0, 0);
  }

  const int rowb = (lane >> 4) << 2;
#pragma unroll
  for (int m = 0; m < 4; ++m)
#pragma unroll
    for (int n = 0; n < 4; ++n) {
      const size_t r0 = m0 + wr * 64 + m * 16 + rowb;
      const size_t cc = n0 + wc * 64 + n * 16 + rsel;
#pragma unroll
      for (int j = 0; j < 4; ++j) {
        const float v = acc[m][n][j];
        if constexpr (sizeof(OutT) == 4)
          C[(r0 + j) * N + cc] = v;
        else
          C[(r0 + j) * N + cc] = __float2bfloat16(v);
      }
    }
}

// ---------------- RoPE + extract Q/K ----------------
__global__ void rope_extract(const __hip_bfloat16* __restrict__ qkv,
                             __hip_bfloat16* __restrict__ Q,
                             __hip_bfloat16* __restrict__ Kr) {
  const int idx = blockIdx.x * 256 + threadIdx.x;
  const int i = idx & 31;
  const int hs = (idx >> 5) % 40;     // 0..31 = Q heads, 32..39 = K heads
  const int r = idx / (40 * 32);      // b*S + s
  const int srow = r & (CS - 1);
  const int b = r >> 11;
  const float inv = exp2f(-(float)i * (13.287712379549449f / 32.0f)); // 10000^(-i/32)
  const float ang = (float)srow * inv;
  const float sn = sinf(ang), cs = cosf(ang);
  const int col = (hs < CNH) ? hs * CHD + 2 * i : CH + (hs - CNH) * CHD + 2 * i;
  const float t1 = __bfloat162float(qkv[(size_t)r * CTHD + col]);
  const float t2 = __bfloat162float(qkv[(size_t)r * CTHD + col + 1]);
  const float ev = t1 * cs - t2 * sn;
  const float ov = t1 * sn + t2 * cs;
  __hip_bfloat16* dst;
  if (hs < CNH)
    dst = Q + ((((size_t)b * CNH + hs) * CS + srow) * CHD + 2 * i);
  else
    dst = Kr + ((((size_t)b * CNKV + (hs - CNH)) * CS + srow) * CHD + 2 * i);
  dst[0] = __float2bfloat16(ev);
  dst[1] = __float2bfloat16(ov);
}

// ---------------- V extract + transpose: VT[b][kvh][d][s] ----------------
__global__ __launch_bounds__(256) void v_transpose(const __hip_bfloat16* __restrict__ qkv,
                                                   __hip_bfloat16* __restrict__ VT) {
  __shared__ __hip_bfloat16 t[64][72];
  const int bi = blockIdx.x;
  const int stile = bi & 31;
  const int kvh = (bi >> 5) & 7;
  const int b = bi >> 8;
  const int tx = threadIdx.x & 63;
  const int ty = threadIdx.x >> 6; // 0..3
  const int s0 = stile * 64;
#pragma unroll
  for (int j = 0; j < 16; ++j) {
    const int sl = ty * 16 + j;
    t[sl][tx] = qkv[(size_t)(b * CS + s0 + sl) * CTHD + (CH + CNKV * CHD) + kvh * CHD + tx];
  }
  __syncthreads();
#pragma unroll
  for (int j = 0; j < 16; ++j) {
    const int dl = ty * 16 + j;
    VT[(((size_t)b * CNKV + kvh) * CHD + dl) * CS + s0 + tx] = t[tx][dl];
  }
}

// ---------------- GQA causal flash attention ----------------
// Block = (b, kvh, qw): 4 waves = the 4 q-heads of the GQA group, all sharing the
// SAME K/V tiles. K+V staged in LDS (double-buffered, global_load_lds with
// pre-swizzled source; read with matching XOR -> ~2-way conflicts). Swapped-operand
// MFMA; lane-local softmax (2 shfl). grid 2048, xcd=kvh, qw heavy-first.
__global__ __launch_bounds__(256) void attn_fa(const __hip_bfloat16* __restrict__ Q,
                                               const __hip_bfloat16* __restrict__ Kr,
                                               const __hip_bfloat16* __restrict__ VT,
                                               const int* __restrict__ mask,
                                               __hip_bfloat16* __restrict__ O) {
  __shared__ __hip_bfloat16 Ks[2][64 * 64];
  __shared__ __hip_bfloat16 Vs[2][64 * 64];
  __shared__ __hip_bfloat16 P4[4][16][72];
  const int kvh = blockIdx.x & 7;          // xcd owns one kv-head
  const int slot = blockIdx.x >> 3;        // 0..255
  const int qw = 127 - (slot >> 1);        // heavy-first
  const int b = slot & 1;
  const int tid = threadIdx.x;
  const int wave = tid >> 6, lane = tid & 63;
  const int h = kvh * 4 + wave;            // this wave's q-head
  const int q0 = qw * 16;
  const int rsel = lane & 15;              // this lane's q-row
  const int hi = lane >> 4;                // 0..3
  const int k8 = hi * 8;
  const int rowb = hi * 4;
  const int qr = q0 + rsel;
  const __hip_bfloat16* Qp = Q + (((size_t)b * CNH + h) * CS + q0) * CHD;
  const __hip_bfloat16* Kp = Kr + ((size_t)b * CNKV + kvh) * CS * CHD;
  const __hip_bfloat16* Vp = VT + ((size_t)b * CNKV + kvh) * CHD * CS;
  const int* mp = mask + b * CS;
  __hip_bfloat16(*P)[72] = P4[wave];

  bf16x8 qf[2];
  qf[0] = *(const bf16x8*)(Qp + rsel * CHD + k8);
  qf[1] = *(const bf16x8*)(Qp + rsel * CHD + 32 + k8);

  f32x4 o[4]; // o[nt][j] = O^T[nt*16+rowb+j][qr]
#pragma unroll
  for (int nt = 0; nt < 4; ++nt) o[nt] = (f32x4){0.f, 0.f, 0.f, 0.f};
  float mrun = -3e38f, lrun = 0.f;

  const int nkb = (qw >> 2) + 1;

  // Stage one 64-key K tile + V tile into LDS buf. LDS dest linear; global source
  // chunk pre-swizzled by (row&7) so the read-side XOR lands on the right data.
  auto stage = [&](int buf, int key0) {
#pragma unroll
    for (int half = 0; half < 2; ++half) {
      const int c = half * 256 + tid;      // 16B chunk index 0..511
      const int r = c >> 3;                // row 0..63
      const int swz = ((c & 7) ^ (r & 7)) * 8;
      __hip_bfloat16* kd = &Ks[buf][(half * 256 + wave * 64) * 8];
      __hip_bfloat16* vd = &Vs[buf][(half * 256 + wave * 64) * 8];
      gload_lds16(Kp + (size_t)(key0 + r) * CHD + swz, kd);
      gload_lds16(Vp + (size_t)r * CS + key0 + swz, vd);
    }
  };

  int mcur = mp[lane], mnext = 0;
  stage(0, 0);
  __syncthreads();

  for (int t = 0; t < nkb; ++t) {
    const int cur = t & 1;
    const int key0 = t * 64;
    const bool last = (t == nkb - 1);
    if (!last) {
      stage(cur ^ 1, key0 + 64);           // prefetch next tile into other buffer
      mnext = mp[key0 + 64 + lane];
    }
    const unsigned long long kvbits = __ballot(mcur > 0);
    const int sz = rsel & 7;
    // K fragments from LDS (swizzled read)
    bf16x8 kc[8];
#pragma unroll
    for (int kt = 0; kt < 4; ++kt) {
      const int row = (kt * 16 + rsel) * 64;
      kc[kt * 2]     = *(const bf16x8*)&Ks[cur][row + ((hi ^ sz) << 3)];
      kc[kt * 2 + 1] = *(const bf16x8*)&Ks[cur][row + (((hi ^ 4) ^ sz) << 3)];
    }
    // S^T = K * Q^T
    f32x4 st[4];
#pragma unroll
    for (int kt = 0; kt < 4; ++kt) {
      f32x4 s = (f32x4){0.f, 0.f, 0.f, 0.f};
      s = __builtin_amdgcn_mfma_f32_16x16x32_bf16(kc[kt * 2], qf[0], s, 0, 0, 0);
      s = __builtin_amdgcn_mfma_f32_16x16x32_bf16(kc[kt * 2 + 1], qf[1], s, 0, 0, 0);
      st[kt] = s;
    }
    // V fragments issued now; consumed after softmax (latency hides under VALU)
    bf16x8 vf[8];
#pragma unroll
    for (int nt = 0; nt < 4; ++nt) {
      const int row = (nt * 16 + rsel) * 64;
      vf[nt * 2]     = *(const bf16x8*)&Vs[cur][row + ((hi ^ sz) << 3)];
      vf[nt * 2 + 1] = *(const bf16x8*)&Vs[cur][row + (((hi ^ 4) ^ sz) << 3)];
    }
    if (kvbits == ~0ull && !last) {
#pragma unroll
      for (int kt = 0; kt < 4; ++kt)
#pragma unroll
        for (int j = 0; j < 4; ++j) st[kt][j] *= 0.125f;
    } else {
#pragma unroll
      for (int kt = 0; kt < 4; ++kt)
#pragma unroll
        for (int j = 0; j < 4; ++j) {
          const int idx = kt * 16 + rowb + j;
          const bool bad = !((kvbits >> idx) & 1ull) || (last && key0 + idx > qr);
          st[kt][j] = bad ? -1e9f : st[kt][j] * 0.125f;
        }
    }
    // lane-local softmax over 16 keys, cross-hi combine via 2 shfl
    float pmax = st[0][0];
#pragma unroll
    for (int kt = 0; kt < 4; ++kt)
#pragma unroll
      for (int j = 0; j < 4; ++j) pmax = fmaxf(pmax, st[kt][j]);
    pmax = fmaxf(pmax, __shfl_xor(pmax, 16));
    pmax = fmaxf(pmax, __shfl_xor(pmax, 32));
    const float mn = fmaxf(mrun, pmax);
    const float al = exp2f((mrun - mn) * 1.44269504f);
    mrun = mn;
    float ps = 0.f;
#pragma unroll
    for (int kt = 0; kt < 4; ++kt)
#pragma unroll
      for (int j = 0; j < 4; ++j) {
        const float p = exp2f((st[kt][j] - mn) * 1.44269504f);
        st[kt][j] = p;
        ps += p;
      }
    ps += __shfl_xor(ps, 16);
    ps += __shfl_xor(ps, 32);
    lrun = lrun * al + ps;
#pragma unroll
    for (int nt = 0; nt < 4; ++nt)
#pragma unroll
      for (int j = 0; j < 4; ++j) o[nt][j] *= al;
    // P^T -> LDS as P[q][key] (8B packed writes), read back as B-fragments
#pragma unroll
    for (int kt = 0; kt < 4; ++kt) {
      ushort4 pk;
      pk.x = bfbits(st[kt][0]);
      pk.y = bfbits(st[kt][1]);
      pk.z = bfbits(st[kt][2]);
      pk.w = bfbits(st[kt][3]);
      *(ushort4*)&P[rsel][kt * 16 + rowb] = pk;
    }
    const bf16x8 pb0 = *(const bf16x8*)&P[rsel][k8];
    const bf16x8 pb1 = *(const bf16x8*)&P[rsel][32 + k8];
    // O^T += V^T * P^T
#pragma unroll
    for (int nt = 0; nt < 4; ++nt) {
      o[nt] = __builtin_amdgcn_mfma_f32_16x16x32_bf16(vf[nt * 2], pb0, o[nt], 0, 0, 0);
      o[nt] = __builtin_amdgcn_mfma_f32_16x16x32_bf16(vf[nt * 2 + 1], pb1, o[nt], 0, 0, 0);
    }
    __syncthreads();
    mcur = mnext;
  }

  const float qm = (mp[qr] > 0) ? 1.0f : 0.0f;
  const float inv = qm / fmaxf(lrun, 1e-20f);
  __hip_bfloat16* Orow = O + (((size_t)b * CS + qr) * CNH + h) * CHD;
#pragma unroll
  for (int nt = 0; nt < 4; ++nt) {
    ushort4 ok;
    ok.x = bfbits(o[nt][0] * inv);
    ok.y = bfbits(o[nt][1] * inv);
    ok.z = bfbits(o[nt][2] * inv);
    ok.w = bfbits(o[nt][3] * inv);
    *(ushort4*)(Orow + nt * 16 + rowb) = ok;
  }
}

extern "C" void kernel_launch(void* const* d_in, const int* in_sizes, int n_in,
                              void* d_out, int out_size, void* d_ws, size_t ws_size,
                              hipStream_t stream) {
  const float* x = (const float*)d_in[0];
  const int* mask = (const int*)d_in[1];
  const float* w_qkv = (const float*)d_in[2];
  const float* w_o = (const float*)d_in[3];
  float* out = (float*)d_out;

  char* ws = (char*)d_ws;
  size_t off = 0;
  auto alloc = [&](size_t bytes) {
    char* p = ws + off;
    off += (bytes + 255) & ~(size_t)255;
    return p;
  };
  const size_t M = (size_t)CB * CS; // 4096
  __hip_bfloat16* x_bf  = (__hip_bfloat16*)alloc(M * CH * 2);
  __hip_bfloat16* wqkvT = (__hip_bfloat16*)alloc((size_t)CTHD * CH * 2);
  __hip_bfloat16* woT   = (__hip_bfloat16*)alloc((size_t)CH * CH * 2);
  __hip_bfloat16* qkv   = (__hip_bfloat16*)alloc(M * CTHD * 2);
  __hip_bfloat16* Qb    = (__hip_bfloat16*)alloc((size_t)CB * CNH * CS * CHD * 2);
  __hip_bfloat16* Kb    = (__hip_bfloat16*)alloc((size_t)CB * CNKV * CS * CHD * 2);
  __hip_bfloat16* VTb   = (__hip_bfloat16*)alloc((size_t)CB * CNKV * CHD * CS * 2);
  __hip_bfloat16* attnb = (__hip_bfloat16*)alloc(M * CH * 2);

  conv_bf16<<<(int)(M * CH / 4 / 256), 256, 0, stream>>>(x, x_bf, (int)(M * CH));
  transpose_conv<<<(CTHD / 32) * (CH / 32), 256, 0, stream>>>(w_qkv, wqkvT, CH, CTHD);
  transpose_conv<<<(CH / 32) * (CH / 32), 256, 0, stream>>>(w_o, woT, CH, CH);
  gemm_bt<__hip_bfloat16><<<(int)(M / 128) * (CTHD / 128), 256, 0, stream>>>(
      x_bf, wqkvT, qkv, (int)M, CTHD, CH);
  rope_extract<<<(int)(M * 40 * 32 / 256), 256, 0, stream>>>(qkv, Qb, Kb);
  v_transpose<<<CB * CNKV * 32, 256, 0, stream>>>(qkv, VTb);
  attn_fa<<<CB * CNKV * 128, 256, 0, stream>>>(Qb, Kb, VTb, mask, attnb);
  gemm_bt<float><<<(int)(M / 128) * (CH / 128), 256, 0, stream>>>(
      attnb, woT, out, (int)M, CH, CH);
}